// Round 8
// baseline (460.352 us; speedup 1.0000x reference)
//
#include <hip/hip_runtime.h>
#include <hip/hip_bf16.h>

#define N_NODES 50000
#define N_EDGES 400000
#define IN_CH 32
#define EPS 1e-5f
#define SCAN_NB ((N_NODES + 1023) / 1024)
#define EL_CAP 1024
#define CHUNK 16

typedef __attribute__((ext_vector_type(8))) short bh8;
typedef __attribute__((ext_vector_type(4))) float fx4;
typedef __attribute__((ext_vector_type(2))) float fx2;

static __device__ __forceinline__ unsigned int f2bf(float f) {
    __hip_bfloat16 h = __float2bfloat16(f);
    return (unsigned int)*(unsigned short*)&h;
}
static __device__ __forceinline__ unsigned short f2bfu(float f) {
    __hip_bfloat16 h = __float2bfloat16(f);
    return *(unsigned short*)&h;
}
static __device__ __forceinline__ float bflo(unsigned int u) { return __uint_as_float(u << 16); }
static __device__ __forceinline__ float bfhi(unsigned int u) { return __uint_as_float(u & 0xffff0000u); }

// ---------------- CSR build ----------------
__global__ void hist_kernel(const int* __restrict__ ei, int* __restrict__ cnt) {
    int e = blockIdx.x * 256 + threadIdx.x;
    if (e < N_EDGES) atomicAdd(&cnt[ei[N_EDGES + e]], 1);
}

__global__ __launch_bounds__(1024) void scan1_kernel(const int* __restrict__ cnt,
                                                     int* __restrict__ exw,
                                                     int* __restrict__ bsum) {
    int b = blockIdx.x, t = threadIdx.x;
    int i = b * 1024 + t;
    int v = (i < N_NODES) ? cnt[i] : 0;
    int lane = t & 63, w = t >> 6;
    int s = v;
    #pragma unroll
    for (int off = 1; off < 64; off <<= 1) {
        int u = __shfl_up(s, off, 64);
        if (lane >= off) s += u;
    }
    __shared__ int ws[16];
    if (lane == 63) ws[w] = s;
    __syncthreads();
    if (t < 16) {
        int sv = ws[t];
        #pragma unroll
        for (int off = 1; off < 16; off <<= 1) {
            int u = __shfl_up(sv, off, 64);
            if (lane >= off) sv += u;
        }
        ws[t] = sv;
    }
    __syncthreads();
    int prefix = (w > 0) ? ws[w - 1] : 0;
    int incl = s + prefix;
    if (i < N_NODES) exw[i] = incl - v;
    if (t == 1023) bsum[b] = incl;
}

__global__ __launch_bounds__(1024) void scan3_kernel(const int* __restrict__ exw,
                                                     const int* __restrict__ bsum,
                                                     int* __restrict__ rp,
                                                     int* __restrict__ cnt) {
    __shared__ int pfx;
    __shared__ int total;
    int b = blockIdx.x, t = threadIdx.x;
    if (t < 64) {
        int v = (t < SCAN_NB) ? bsum[t] : 0;
        #pragma unroll
        for (int off = 1; off < 64; off <<= 1) {
            int u = __shfl_up(v, off, 64);
            if (t >= off) v += u;
        }
        if (b == 0 && t == 0) pfx = 0;
        if (b > 0 && t == b - 1) pfx = v;
        if (t == SCAN_NB - 1) total = v;
    }
    __syncthreads();
    int i = b * 1024 + t;
    if (i < N_NODES) {
        rp[i] = exw[i] + pfx;
        cnt[i] = 0;
    }
    if (b == 0 && t == 0) rp[N_NODES] = total;
}

__global__ void fill_kernel(const int* __restrict__ ei, const int* __restrict__ rp,
                            int* __restrict__ cur, int* __restrict__ el) {
    int e = blockIdx.x * 256 + threadIdx.x;
    if (e < N_EDGES) {
        int d = ei[N_EDGES + e];
        int p = atomicAdd(&cur[d], 1);
        el[rp[d] + p] = ei[e];
    }
}

// ---------------- merged weight prepacks ----------------
#define WCT_TOT (3 * 320 * 64)
#define W2T_TOT (3 * 64 * 128)
__global__ void repack_kernel(const float* __restrict__ W1, const float* __restrict__ Wr,
                              const float* __restrict__ W2,
                              unsigned short* __restrict__ WcT,
                              unsigned short* __restrict__ W2T) {
    int t = blockIdx.x * 256 + threadIdx.x;
    if (t < WCT_TOT) {
        int l = t / (320 * 64);
        int rem = t % (320 * 64);
        int j = rem / 64, c = rem % 64;
        float v;
        if (j < 128)      v = W1[(l * 128 + c) * 128 + j];
        else if (j < 256) v = W1[(l * 128 + 64 + c) * 128 + (j - 128)];
        else              v = Wr[(l * 64 + c) * 64 + (j - 256)];
        WcT[t] = f2bfu(v);
    } else if (t < WCT_TOT + W2T_TOT) {
        int t2 = t - WCT_TOT;
        int l = t2 / 8192, rem = t2 % 8192;
        int n = rem / 128, k = rem % 128;
        W2T[t2] = f2bfu(W2[l * 8192 + k * 64 + n]);
    }
}

// ---------------- encoder ----------------
__global__ __launch_bounds__(256) void encoder_kernel(
    const float* __restrict__ x, const float* __restrict__ W,
    const float* __restrict__ b, const float* __restrict__ g,
    const float* __restrict__ beta, float* __restrict__ out) {
    __shared__ float wlds[IN_CH * 64];
    for (int t = threadIdx.x; t < IN_CH * 64; t += 256) wlds[t] = W[t];
    __syncthreads();
    int lane = threadIdx.x & 63;
    int node = blockIdx.x * 4 + (threadIdx.x >> 6);
    if (node >= N_NODES) return;
    float xv = (lane < IN_CH) ? x[node * IN_CH + lane] : 0.f;
    float acc = b[lane];
    #pragma unroll
    for (int c = 0; c < IN_CH; ++c) {
        float xc = __shfl(xv, c, 64);
        acc += xc * wlds[c * 64 + lane];
    }
    float s = acc;
    for (int off = 32; off; off >>= 1) s += __shfl_xor(s, off, 64);
    float mu = s * (1.f / 64.f);
    float d = acc - mu;
    float q = d * d;
    for (int off = 32; off; off >>= 1) q += __shfl_xor(q, off, 64);
    float r = rsqrtf(q * (1.f / 64.f) + EPS);
    out[node * 64 + lane] = d * r * g[lane] + beta[lane];
}

// ---------------- fused5: wave-per-edge segmented gather -> update -> LN+ReLU -> GEMM
// mode 0: LN+GEMM only. mode 1: full. mode 2: gather+update only.
__global__ __launch_bounds__(256, 4) void fused5_kernel(
    float* __restrict__ x,
    const unsigned short* __restrict__ AbfI, const unsigned char* __restrict__ B8I,
    const unsigned short* __restrict__ W2T, const float* __restrict__ b2,
    const int* __restrict__ rp, const int* __restrict__ el,
    const float* __restrict__ g, const float* __restrict__ bvec,
    const unsigned short* __restrict__ WcT, const float* __restrict__ b1,
    unsigned short* __restrict__ AbfO, unsigned char* __restrict__ B8O,
    unsigned short* __restrict__ Rbf, int mode) {
    __shared__ float slds_f[32][132];       // gathered S tile (fp32), padded stride
    __shared__ unsigned int A_lds[32][64];  // own-node A rows (bf16 pairs)
    __shared__ int el_lds[EL_CAP];
    __shared__ unsigned char dst_lds[EL_CAP];
    __shared__ int rp_lds[33];
    __shared__ float bufF[2][1088];         // per-stripe: xf stride 68 ; then h stride 33
    int tid = threadIdx.x;
    int lane = tid & 63, wid = tid >> 6;
    int l15 = lane & 15, g4 = lane >> 4;
    int stripe = wid >> 1, half = wid & 1;
    int base = blockIdx.x * 32;
    int row0 = base + stripe * 16;
    float* xf = &bufF[stripe][0];
    unsigned int* hU = (unsigned int*)&bufF[stripe][0];
    int n = tid >> 3, sq = tid & 7;

    if (mode != 0) {
        if (tid < 33) rp_lds[tid] = rp[min(base + tid, N_NODES)];
        __syncthreads();
        int e0 = rp_lds[0];
        int nE = rp_lds[32] - e0;
        bool inl = (nE <= EL_CAP);

        // zero S tile
        for (int t = tid; t < 32 * 132; t += 256) ((float*)slds_f)[t] = 0.f;
        // stage own-node A rows (coalesced)
        {
            int nd = base + n;
            uint4 a0 = make_uint4(0, 0, 0, 0), a1 = a0;
            if (nd < N_NODES) {
                a0 = *(const uint4*)(AbfI + (size_t)nd * 128 + sq * 16);
                a1 = *(const uint4*)(AbfI + (size_t)nd * 128 + sq * 16 + 8);
            }
            *(uint4*)&A_lds[n][sq * 8] = a0;
            *(uint4*)&A_lds[n][sq * 8 + 4] = a1;
        }
        // stage edge list + per-edge dst-local (binary search over rp_lds)
        if (inl) {
            for (int t = tid; t < nE; t += 256) {
                el_lds[t] = el[e0 + t];
                int ge = e0 + t;
                int lo = 0, hi = 32;
                #pragma unroll
                for (int s = 0; s < 5; ++s) {
                    int mid = (lo + hi) >> 1;
                    if (rp_lds[mid] <= ge) lo = mid; else hi = mid;
                }
                dst_lds[t] = (unsigned char)lo;
            }
        }

        // early-issue epilogue operands
        int nd_l = row0 + g4 * 4;
        int cols[2];
        #pragma unroll
        for (int j = 0; j < 2; ++j) cols[j] = (half * 2 + j) * 16 + l15;
        float xpre[2][4], rpre[2][4];
        #pragma unroll
        for (int j = 0; j < 2; ++j)
            #pragma unroll
            for (int r = 0; r < 4; ++r) {
                int nd = min(nd_l + r, N_NODES - 1);
                xpre[j][r] = x[(size_t)nd * 64 + cols[j]];
                rpre[j][r] = bflo((unsigned int)Rbf[(size_t)nd * 64 + cols[j]]);
            }
        __syncthreads();

        // ---- segmented edge gather: wave takes contiguous quarter of edge list ----
        auto getsrc = [&](int idx) -> int {
            return inl ? el_lds[idx] : el[e0 + idx];
        };
        auto getdst = [&](int idx) -> int {
            if (inl) return (int)dst_lds[idx];
            int ge = e0 + idx;
            int lo = 0, hi = 32;
            #pragma unroll
            for (int s = 0; s < 5; ++s) {
                int mid = (lo + hi) >> 1;
                if (rp_lds[mid] <= ge) lo = mid; else hi = mid;
            }
            return lo;
        };
        int per = (nE + 3) >> 2;
        int wss = min(wid * per, nE);
        int wee = min(wss + per, nE);
        float accx = 0.f, accy = 0.f, ax = 0.f, ay = 0.f;
        int cur = -1;
        unsigned short bufc[CHUNK], buf2[CHUNK];
        int i = wss;
        int cn = wee - i; if (cn > CHUNK) cn = CHUNK;
        #pragma unroll
        for (int j = 0; j < CHUNK; ++j)
            if (j < cn) {
                int src = getsrc(i + j);
                bufc[j] = *(const unsigned short*)(B8I + (size_t)src * 128 + lane * 2);
            }
        while (cn > 0) {
            int ni = i + cn;
            int nn = wee - ni; if (nn > CHUNK) nn = CHUNK; if (nn < 0) nn = 0;
            #pragma unroll
            for (int j = 0; j < CHUNK; ++j)
                if (j < nn) {
                    int src = getsrc(ni + j);
                    buf2[j] = *(const unsigned short*)(B8I + (size_t)src * 128 + lane * 2);
                }
            #pragma unroll
            for (int j = 0; j < CHUNK; ++j)
                if (j < cn) {
                    int d = getdst(i + j);
                    if (d != cur) {
                        if (cur >= 0) {
                            atomicAdd(&slds_f[cur][2 * lane], accx);
                            atomicAdd(&slds_f[cur][2 * lane + 1], accy);
                        }
                        cur = d; accx = 0.f; accy = 0.f;
                        unsigned int au = A_lds[d][lane];
                        ax = bflo(au); ay = bfhi(au);
                    }
                    fx2 f = __builtin_amdgcn_cvt_pk_f32_fp8((int)bufc[j], false);
                    accx += fmaxf(ax + f.x, 0.f);
                    accy += fmaxf(ay + f.y, 0.f);
                }
            #pragma unroll
            for (int j = 0; j < CHUNK; ++j) bufc[j] = buf2[j];
            i = ni; cn = nn;
        }
        if (cur >= 0) {
            atomicAdd(&slds_f[cur][2 * lane], accx);
            atomicAdd(&slds_f[cur][2 * lane + 1], accy);
        }
        __syncthreads();

        // ---- S(16x128) @ W2T -> update x ----
        int arow = stripe * 16 + l15;
        bh8 sa[4];
        #pragma unroll
        for (int ks = 0; ks < 4; ++ks) {
            fx4 t0 = *(const fx4*)&slds_f[arow][ks * 32 + g4 * 8];
            fx4 t1 = *(const fx4*)&slds_f[arow][ks * 32 + g4 * 8 + 4];
            bh8 v;
            v[0] = (short)f2bfu(t0[0]); v[1] = (short)f2bfu(t0[1]);
            v[2] = (short)f2bfu(t0[2]); v[3] = (short)f2bfu(t0[3]);
            v[4] = (short)f2bfu(t1[0]); v[5] = (short)f2bfu(t1[1]);
            v[6] = (short)f2bfu(t1[2]); v[7] = (short)f2bfu(t1[3]);
            sa[ks] = v;
        }
        fx4 accm[2];
        #pragma unroll
        for (int j = 0; j < 2; ++j) {
            int nb = half * 2 + j;
            accm[j] = (fx4){0.f, 0.f, 0.f, 0.f};
            #pragma unroll
            for (int ks = 0; ks < 4; ++ks) {
                bh8 bf = *(const bh8*)(W2T + ((size_t)(nb * 16 + l15) * 128 + ks * 32 + g4 * 8));
                accm[j] = __builtin_amdgcn_mfma_f32_16x16x32_bf16(sa[ks], bf, accm[j], 0, 0, 0);
            }
        }
        float inv[4], msk[4];
        #pragma unroll
        for (int r = 0; r < 4; ++r) {
            int lcl = stripe * 16 + g4 * 4 + r;
            int cv = rp_lds[lcl + 1] - rp_lds[lcl];
            inv[r] = cv > 0 ? 1.f / (float)cv : 0.f;
            msk[r] = cv > 0 ? 1.f : 0.f;
        }
        #pragma unroll
        for (int j = 0; j < 2; ++j) {
            float b2c = b2[cols[j]];
            #pragma unroll
            for (int r = 0; r < 4; ++r) {
                int nd = nd_l + r;
                float xn = xpre[j][r] + accm[j][r] * inv[r] + b2c * msk[r] + rpre[j][r];
                if (nd < N_NODES) x[(size_t)nd * 64 + cols[j]] = xn;
                if (mode == 1) xf[(g4 * 4 + r) * 68 + cols[j]] = xn;
            }
        }
        if (mode == 2) return;
        __syncthreads();
    }

    // ---- LN + ReLU: 8 threads per row, write h bf16x2 at stride 33 ----
    {
        int lstripe = n >> 4, lr = n & 15;
        float vv[8];
        if (mode == 0) {
            int nd = base + n;
            float4 v0 = make_float4(0.f, 0.f, 0.f, 0.f), v1 = v0;
            if (nd < N_NODES) {
                v0 = ((const float4*)(x + (size_t)nd * 64 + sq * 8))[0];
                v1 = ((const float4*)(x + (size_t)nd * 64 + sq * 8))[1];
            }
            vv[0] = v0.x; vv[1] = v0.y; vv[2] = v0.z; vv[3] = v0.w;
            vv[4] = v1.x; vv[5] = v1.y; vv[6] = v1.z; vv[7] = v1.w;
        } else {
            #pragma unroll
            for (int i2 = 0; i2 < 8; ++i2) vv[i2] = bufF[lstripe][lr * 68 + sq * 8 + i2];
        }
        float s = 0.f;
        #pragma unroll
        for (int i2 = 0; i2 < 8; ++i2) s += vv[i2];
        s += __shfl_xor(s, 1, 8);
        s += __shfl_xor(s, 2, 8);
        s += __shfl_xor(s, 4, 8);
        float mu = s * (1.f / 64.f);
        float q = 0.f;
        #pragma unroll
        for (int i2 = 0; i2 < 8; ++i2) { float d = vv[i2] - mu; q += d * d; }
        q += __shfl_xor(q, 1, 8);
        q += __shfl_xor(q, 2, 8);
        q += __shfl_xor(q, 4, 8);
        float rs = rsqrtf(q * (1.f / 64.f) + EPS);
        float4 g0 = *(const float4*)&g[sq * 8], g1 = *(const float4*)&g[sq * 8 + 4];
        float4 b0 = *(const float4*)&bvec[sq * 8], b1v = *(const float4*)&bvec[sq * 8 + 4];
        float gv[8] = {g0.x, g0.y, g0.z, g0.w, g1.x, g1.y, g1.z, g1.w};
        float bv[8] = {b0.x, b0.y, b0.z, b0.w, b1v.x, b1v.y, b1v.z, b1v.w};
        __syncthreads();
        unsigned int* hw = (unsigned int*)&bufF[lstripe][0];
        #pragma unroll
        for (int jj = 0; jj < 4; ++jj) {
            float h0 = fmaxf((vv[2 * jj] - mu) * rs * gv[2 * jj] + bv[2 * jj], 0.f);
            float h1 = fmaxf((vv[2 * jj + 1] - mu) * rs * gv[2 * jj + 1] + bv[2 * jj + 1], 0.f);
            hw[lr * 33 + sq * 4 + jj] = f2bf(h0) | (f2bf(h1) << 16);
        }
    }
    __syncthreads();

    // ---- GEMM2: h(16x64) @ Wc(64x320); wave does 10 of 20 col-blocks ----
    bh8 a2[2];
    #pragma unroll
    for (int ks = 0; ks < 2; ++ks)
        a2[ks] = *(const bh8*)&hU[l15 * 33 + ks * 16 + g4 * 4];
    int ndg = row0 + g4 * 4;
    #pragma unroll 2
    for (int nn = 0; nn < 10; ++nn) {
        int nb = half * 10 + nn;
        fx4 c = (fx4){0.f, 0.f, 0.f, 0.f};
        #pragma unroll
        for (int ks = 0; ks < 2; ++ks) {
            bh8 bf = *(const bh8*)(WcT + ((size_t)(nb * 16 + l15) * 64 + ks * 32 + g4 * 8));
            c = __builtin_amdgcn_mfma_f32_16x16x32_bf16(a2[ks], bf, c, 0, 0, 0);
        }
        int col = nb * 16 + l15;
        #pragma unroll
        for (int r = 0; r < 4; ++r) {
            int nd = ndg + r;
            if (nd >= N_NODES) continue;
            float v = c[r];
            if (col < 128) {
                AbfO[(size_t)nd * 128 + col] = f2bfu(v + b1[col]);
            } else if (col < 256) {
                unsigned int p = __builtin_amdgcn_cvt_pk_fp8_f32(v, v, 0, false);
                B8O[(size_t)nd * 128 + (col - 128)] = (unsigned char)(p & 0xFF);
            } else {
                Rbf[(size_t)nd * 64 + (col - 256)] = f2bfu(v);
            }
        }
    }
}

extern "C" void kernel_launch(void* const* d_in, const int* in_sizes, int n_in,
                              void* d_out, int out_size, void* d_ws, size_t ws_size,
                              hipStream_t stream) {
    const float* x       = (const float*)d_in[0];
    const int*   ei      = (const int*)d_in[1];
    const float* encW    = (const float*)d_in[2];
    const float* encb    = (const float*)d_in[3];
    const float* encg    = (const float*)d_in[4];
    const float* encbeta = (const float*)d_in[5];
    const float* lng     = (const float*)d_in[6];
    const float* lnb     = (const float*)d_in[7];
    const float* W1      = (const float*)d_in[8];
    const float* b1      = (const float*)d_in[9];
    const float* W2      = (const float*)d_in[10];
    const float* b2      = (const float*)d_in[11];
    const float* Wr      = (const float*)d_in[12];
    float* xout = (float*)d_out;

    char* ws = (char*)d_ws;
    size_t off = 0;
    auto alloc = [&](size_t bytes) -> void* {
        void* p = ws + off;
        off += (bytes + 255) & ~(size_t)255;
        return p;
    };
    unsigned short* WcT  = (unsigned short*)alloc(3 * 320 * 64 * sizeof(unsigned short));
    unsigned short* W2T  = (unsigned short*)alloc(3 * 64 * 128 * sizeof(unsigned short));
    unsigned short* Abf0 = (unsigned short*)alloc((size_t)N_NODES * 128 * sizeof(unsigned short));
    unsigned short* Abf1 = (unsigned short*)alloc((size_t)N_NODES * 128 * sizeof(unsigned short));
    unsigned char*  B80  = (unsigned char*)alloc((size_t)N_NODES * 128);
    unsigned char*  B81  = (unsigned char*)alloc((size_t)N_NODES * 128);
    unsigned short* Rbf  = (unsigned short*)alloc((size_t)N_NODES * 64 * sizeof(unsigned short));
    int*            cnt  = (int*)alloc(N_NODES * sizeof(int));
    int*            rp   = (int*)alloc((N_NODES + 1) * sizeof(int));
    int*            el   = (int*)alloc(N_EDGES * sizeof(int));
    int*            exw  = (int*)alloc(N_NODES * sizeof(int));
    int*            bsum = (int*)alloc(SCAN_NB * sizeof(int));

    hipMemsetAsync(cnt, 0, N_NODES * sizeof(int), stream);
    hist_kernel<<<(N_EDGES + 255) / 256, 256, 0, stream>>>(ei, cnt);
    scan1_kernel<<<SCAN_NB, 1024, 0, stream>>>(cnt, exw, bsum);
    scan3_kernel<<<SCAN_NB, 1024, 0, stream>>>(exw, bsum, rp, cnt);
    fill_kernel<<<(N_EDGES + 255) / 256, 256, 0, stream>>>(ei, rp, cnt, el);
    repack_kernel<<<(WCT_TOT + W2T_TOT + 255) / 256, 256, 0, stream>>>(W1, Wr, W2, WcT, W2T);

    encoder_kernel<<<(N_NODES + 3) / 4, 256, 0, stream>>>(x, encW, encb, encg, encbeta, xout);

    int gblocks = (N_NODES + 31) / 32;
    // layer 0: LN+GEMM only, writes pair0
    fused5_kernel<<<gblocks, 256, 0, stream>>>(
        xout, Abf0, B80, W2T, b2, rp, el, lng, lnb,
        WcT, b1, Abf0, B80, Rbf, 0);
    // layer 1: gather pair0 (layer0 W2), writes pair1
    fused5_kernel<<<gblocks, 256, 0, stream>>>(
        xout, Abf0, B80, W2T, b2, rp, el, lng + 64, lnb + 64,
        WcT + (size_t)1 * 320 * 64, b1 + 128, Abf1, B81, Rbf, 1);
    // layer 2: gather pair1 (layer1 W2), writes pair0
    fused5_kernel<<<gblocks, 256, 0, stream>>>(
        xout, Abf1, B81, W2T + (size_t)1 * 64 * 128, b2 + 64, rp, el, lng + 128, lnb + 128,
        WcT + (size_t)2 * 320 * 64, b1 + 256, Abf0, B80, Rbf, 1);
    // final: gather pair0 (layer2 W2), update only
    fused5_kernel<<<gblocks, 256, 0, stream>>>(
        xout, Abf0, B80, W2T + (size_t)2 * 64 * 128, b2 + 128, rp, el, lng, lnb,
        WcT, b1, Abf1, B81, Rbf, 2);
}

// Round 9
// 247.740 us; speedup vs baseline: 1.8582x; 1.8582x over previous
//
#include <hip/hip_runtime.h>
#include <hip/hip_bf16.h>

#define N_NODES 50000
#define N_EDGES 400000
#define IN_CH 32
#define EPS 1e-5f
#define SCAN_NB ((N_NODES + 1023) / 1024)
#define EL_CAP 1024

typedef __attribute__((ext_vector_type(8))) short bh8;
typedef __attribute__((ext_vector_type(4))) float fx4;
typedef __attribute__((ext_vector_type(2))) float fx2;

static __device__ __forceinline__ unsigned int f2bf(float f) {
    __hip_bfloat16 h = __float2bfloat16(f);
    return (unsigned int)*(unsigned short*)&h;
}
static __device__ __forceinline__ unsigned short f2bfu(float f) {
    __hip_bfloat16 h = __float2bfloat16(f);
    return *(unsigned short*)&h;
}
static __device__ __forceinline__ float bflo(unsigned int u) { return __uint_as_float(u << 16); }
static __device__ __forceinline__ float bfhi(unsigned int u) { return __uint_as_float(u & 0xffff0000u); }

// ---------------- CSR build ----------------
__global__ void hist_kernel(const int* __restrict__ ei, int* __restrict__ cnt) {
    int e = blockIdx.x * 256 + threadIdx.x;
    if (e < N_EDGES) atomicAdd(&cnt[ei[N_EDGES + e]], 1);
}

__global__ __launch_bounds__(1024) void scan1_kernel(const int* __restrict__ cnt,
                                                     int* __restrict__ exw,
                                                     int* __restrict__ bsum) {
    int b = blockIdx.x, t = threadIdx.x;
    int i = b * 1024 + t;
    int v = (i < N_NODES) ? cnt[i] : 0;
    int lane = t & 63, w = t >> 6;
    int s = v;
    #pragma unroll
    for (int off = 1; off < 64; off <<= 1) {
        int u = __shfl_up(s, off, 64);
        if (lane >= off) s += u;
    }
    __shared__ int ws[16];
    if (lane == 63) ws[w] = s;
    __syncthreads();
    if (t < 16) {
        int sv = ws[t];
        #pragma unroll
        for (int off = 1; off < 16; off <<= 1) {
            int u = __shfl_up(sv, off, 64);
            if (lane >= off) sv += u;
        }
        ws[t] = sv;
    }
    __syncthreads();
    int prefix = (w > 0) ? ws[w - 1] : 0;
    int incl = s + prefix;
    if (i < N_NODES) exw[i] = incl - v;
    if (t == 1023) bsum[b] = incl;
}

__global__ __launch_bounds__(1024) void scan3_kernel(const int* __restrict__ exw,
                                                     const int* __restrict__ bsum,
                                                     int* __restrict__ rp,
                                                     int* __restrict__ cnt) {
    __shared__ int pfx;
    __shared__ int total;
    int b = blockIdx.x, t = threadIdx.x;
    if (t < 64) {
        int v = (t < SCAN_NB) ? bsum[t] : 0;
        #pragma unroll
        for (int off = 1; off < 64; off <<= 1) {
            int u = __shfl_up(v, off, 64);
            if (t >= off) v += u;
        }
        if (b == 0 && t == 0) pfx = 0;
        if (b > 0 && t == b - 1) pfx = v;
        if (t == SCAN_NB - 1) total = v;
    }
    __syncthreads();
    int i = b * 1024 + t;
    if (i < N_NODES) {
        rp[i] = exw[i] + pfx;
        cnt[i] = 0;
    }
    if (b == 0 && t == 0) rp[N_NODES] = total;
}

__global__ void fill_kernel(const int* __restrict__ ei, const int* __restrict__ rp,
                            int* __restrict__ cur, int* __restrict__ el) {
    int e = blockIdx.x * 256 + threadIdx.x;
    if (e < N_EDGES) {
        int d = ei[N_EDGES + e];
        int p = atomicAdd(&cur[d], 1);
        el[rp[d] + p] = ei[e];
    }
}

// ---------------- merged weight prepacks ----------------
#define WCT_TOT (3 * 320 * 64)
#define W2T_TOT (3 * 64 * 128)
__global__ void repack_kernel(const float* __restrict__ W1, const float* __restrict__ Wr,
                              const float* __restrict__ W2,
                              unsigned short* __restrict__ WcT,
                              unsigned short* __restrict__ W2T) {
    int t = blockIdx.x * 256 + threadIdx.x;
    if (t < WCT_TOT) {
        int l = t / (320 * 64);
        int rem = t % (320 * 64);
        int j = rem / 64, c = rem % 64;
        float v;
        if (j < 128)      v = W1[(l * 128 + c) * 128 + j];
        else if (j < 256) v = W1[(l * 128 + 64 + c) * 128 + (j - 128)];
        else              v = Wr[(l * 64 + c) * 64 + (j - 256)];
        WcT[t] = f2bfu(v);
    } else if (t < WCT_TOT + W2T_TOT) {
        int t2 = t - WCT_TOT;
        int l = t2 / 8192, rem = t2 % 8192;
        int n = rem / 128, k = rem % 128;
        W2T[t2] = f2bfu(W2[l * 8192 + k * 64 + n]);
    }
}

// ---------------- encoder ----------------
__global__ __launch_bounds__(256) void encoder_kernel(
    const float* __restrict__ x, const float* __restrict__ W,
    const float* __restrict__ b, const float* __restrict__ g,
    const float* __restrict__ beta, float* __restrict__ out) {
    __shared__ float wlds[IN_CH * 64];
    for (int t = threadIdx.x; t < IN_CH * 64; t += 256) wlds[t] = W[t];
    __syncthreads();
    int lane = threadIdx.x & 63;
    int node = blockIdx.x * 4 + (threadIdx.x >> 6);
    if (node >= N_NODES) return;
    float xv = (lane < IN_CH) ? x[node * IN_CH + lane] : 0.f;
    float acc = b[lane];
    #pragma unroll
    for (int c = 0; c < IN_CH; ++c) {
        float xc = __shfl(xv, c, 64);
        acc += xc * wlds[c * 64 + lane];
    }
    float s = acc;
    for (int off = 32; off; off >>= 1) s += __shfl_xor(s, off, 64);
    float mu = s * (1.f / 64.f);
    float d = acc - mu;
    float q = d * d;
    for (int off = 32; off; off >>= 1) q += __shfl_xor(q, off, 64);
    float r = rsqrtf(q * (1.f / 64.f) + EPS);
    out[node * 64 + lane] = d * r * g[lane] + beta[lane];
}

// ---------------- fused6: [gather S (own 32 nodes, 8-deep pipeline) -> update] -> LN+ReLU -> GEMM
// mode 0: LN+GEMM only. mode 1: full. mode 2: gather+update only.
__global__ __launch_bounds__(256, 4) void fused6_kernel(
    float* __restrict__ x,
    const unsigned short* __restrict__ AbfI, const unsigned char* __restrict__ B8I,
    const unsigned short* __restrict__ W2T, const float* __restrict__ b2,
    const int* __restrict__ rp, const int* __restrict__ el,
    const float* __restrict__ g, const float* __restrict__ bvec,
    const unsigned short* __restrict__ WcT, const float* __restrict__ b1,
    unsigned short* __restrict__ AbfO, unsigned char* __restrict__ B8O,
    unsigned short* __restrict__ Rbf, int mode) {
    __shared__ float bufF[2][1088];        // per-stripe: xf stride 68 ; then h stride 33 (uints)
    __shared__ unsigned int slds[32][68];  // gathered S tile, bf16 pairs
    __shared__ int el_lds[EL_CAP];
    __shared__ int rp_lds[33];
    int tid = threadIdx.x;
    int lane = tid & 63, wid = tid >> 6;
    int l15 = lane & 15, g4 = lane >> 4;
    int stripe = wid >> 1, half = wid & 1;
    int base = blockIdx.x * 32;
    int row0 = base + stripe * 16;
    float* xf = &bufF[stripe][0];
    unsigned int* hU = (unsigned int*)&bufF[stripe][0];
    int n = tid >> 3, sq = tid & 7;  // gather/LN mapping: 8 threads per row

    int nd_l = row0 + g4 * 4;
    int cols[2];
    #pragma unroll
    for (int j = 0; j < 2; ++j) cols[j] = (half * 2 + j) * 16 + l15;
    float xpre[2][4], rpre[2][4];

    if (mode != 0) {
        if (tid < 33) rp_lds[tid] = rp[min(base + tid, N_NODES)];
        __syncthreads();
        int e0 = rp_lds[0];
        int nE = rp_lds[32] - e0;
        bool inl = (nE <= EL_CAP);
        if (inl) for (int t = tid; t < nE; t += 256) el_lds[t] = el[e0 + t];

        // own-node A row (16 cols per thread)
        int nd_g = base + n;
        float av[16], acc[16];
        #pragma unroll
        for (int i = 0; i < 16; ++i) { av[i] = 0.f; acc[i] = 0.f; }
        if (nd_g < N_NODES) {
            uint4 a0 = *(const uint4*)(AbfI + (size_t)nd_g * 128 + sq * 16);
            uint4 a1 = *(const uint4*)(AbfI + (size_t)nd_g * 128 + sq * 16 + 8);
            unsigned int aw[8] = {a0.x, a0.y, a0.z, a0.w, a1.x, a1.y, a1.z, a1.w};
            #pragma unroll
            for (int q = 0; q < 8; ++q) { av[2 * q] = bflo(aw[q]); av[2 * q + 1] = bfhi(aw[q]); }
        }
        __syncthreads();  // el_lds ready

        // ---- 8-deep batched gather pipeline ----
        int es = rp_lds[n] - e0, ee = rp_lds[n + 1] - e0;
        int e2 = es;
        int cn = ee - e2; if (cn > 8) cn = 8;
        uint4 bufv[8];
        #pragma unroll
        for (int j = 0; j < 8; ++j)
            if (j < cn) {
                int src = inl ? el_lds[e2 + j] : el[e0 + e2 + j];
                bufv[j] = *(const uint4*)(B8I + (size_t)src * 128 + sq * 16);
            }
        while (cn > 0) {
            #pragma unroll
            for (int j = 0; j < 8; ++j)
                if (j < cn) {
                    unsigned int w[4] = {bufv[j].x, bufv[j].y, bufv[j].z, bufv[j].w};
                    #pragma unroll
                    for (int q = 0; q < 4; ++q) {
                        fx2 f0 = __builtin_amdgcn_cvt_pk_f32_fp8((int)w[q], false);
                        fx2 f1 = __builtin_amdgcn_cvt_pk_f32_fp8((int)w[q], true);
                        acc[4 * q + 0] += fmaxf(av[4 * q + 0] + f0.x, 0.f);
                        acc[4 * q + 1] += fmaxf(av[4 * q + 1] + f0.y, 0.f);
                        acc[4 * q + 2] += fmaxf(av[4 * q + 2] + f1.x, 0.f);
                        acc[4 * q + 3] += fmaxf(av[4 * q + 3] + f1.y, 0.f);
                    }
                }
            e2 += cn;
            cn = ee - e2; if (cn > 8) cn = 8;
            #pragma unroll
            for (int j = 0; j < 8; ++j)
                if (j < cn) {
                    int src = inl ? el_lds[e2 + j] : el[e0 + e2 + j];
                    bufv[j] = *(const uint4*)(B8I + (size_t)src * 128 + sq * 16);
                }
        }
        #pragma unroll
        for (int j = 0; j < 8; ++j)
            slds[n][sq * 8 + j] = f2bf(acc[2 * j]) | (f2bf(acc[2 * j + 1]) << 16);

        // issue epilogue operand loads now (overlap with barrier + MFMA)
        #pragma unroll
        for (int j = 0; j < 2; ++j)
            #pragma unroll
            for (int r = 0; r < 4; ++r) {
                int nd = min(nd_l + r, N_NODES - 1);
                xpre[j][r] = x[(size_t)nd * 64 + cols[j]];
                rpre[j][r] = bflo((unsigned int)Rbf[(size_t)nd * 64 + cols[j]]);
            }
        __syncthreads();

        // ---- S(16x128) @ W2T -> update x ----
        bh8 sa[4];
        #pragma unroll
        for (int ks = 0; ks < 4; ++ks)
            sa[ks] = *(const bh8*)&slds[stripe * 16 + l15][ks * 16 + g4 * 4];
        fx4 accm[2];
        #pragma unroll
        for (int j = 0; j < 2; ++j) {
            int nb = half * 2 + j;
            accm[j] = (fx4){0.f, 0.f, 0.f, 0.f};
            #pragma unroll
            for (int ks = 0; ks < 4; ++ks) {
                bh8 bf = *(const bh8*)(W2T + ((size_t)(nb * 16 + l15) * 128 + ks * 32 + g4 * 8));
                accm[j] = __builtin_amdgcn_mfma_f32_16x16x32_bf16(sa[ks], bf, accm[j], 0, 0, 0);
            }
        }
        float inv[4], msk[4];
        #pragma unroll
        for (int r = 0; r < 4; ++r) {
            int lcl = stripe * 16 + g4 * 4 + r;
            int cv = rp_lds[lcl + 1] - rp_lds[lcl];
            inv[r] = cv > 0 ? 1.f / (float)cv : 0.f;
            msk[r] = cv > 0 ? 1.f : 0.f;
        }
        #pragma unroll
        for (int j = 0; j < 2; ++j) {
            float b2c = b2[cols[j]];
            #pragma unroll
            for (int r = 0; r < 4; ++r) {
                int nd = nd_l + r;
                float xn = xpre[j][r] + accm[j][r] * inv[r] + b2c * msk[r] + rpre[j][r];
                if (nd < N_NODES) x[(size_t)nd * 64 + cols[j]] = xn;
                if (mode == 1) xf[(g4 * 4 + r) * 68 + cols[j]] = xn;
            }
        }
        if (mode == 2) return;
        __syncthreads();
    }

    // ---- LN + ReLU: 8 threads per row, write h bf16x2 at stride 33 ----
    {
        int lstripe = n >> 4, lr = n & 15;
        float vv[8];
        if (mode == 0) {
            int nd = base + n;
            float4 v0 = make_float4(0.f, 0.f, 0.f, 0.f), v1 = v0;
            if (nd < N_NODES) {
                v0 = ((const float4*)(x + (size_t)nd * 64 + sq * 8))[0];
                v1 = ((const float4*)(x + (size_t)nd * 64 + sq * 8))[1];
            }
            vv[0] = v0.x; vv[1] = v0.y; vv[2] = v0.z; vv[3] = v0.w;
            vv[4] = v1.x; vv[5] = v1.y; vv[6] = v1.z; vv[7] = v1.w;
        } else {
            #pragma unroll
            for (int i = 0; i < 8; ++i) vv[i] = bufF[lstripe][lr * 68 + sq * 8 + i];
        }
        float s = 0.f;
        #pragma unroll
        for (int i = 0; i < 8; ++i) s += vv[i];
        s += __shfl_xor(s, 1, 8);
        s += __shfl_xor(s, 2, 8);
        s += __shfl_xor(s, 4, 8);
        float mu = s * (1.f / 64.f);
        float q = 0.f;
        #pragma unroll
        for (int i = 0; i < 8; ++i) { float d = vv[i] - mu; q += d * d; }
        q += __shfl_xor(q, 1, 8);
        q += __shfl_xor(q, 2, 8);
        q += __shfl_xor(q, 4, 8);
        float rs = rsqrtf(q * (1.f / 64.f) + EPS);
        float4 g0 = *(const float4*)&g[sq * 8], g1 = *(const float4*)&g[sq * 8 + 4];
        float4 b0 = *(const float4*)&bvec[sq * 8], b1v = *(const float4*)&bvec[sq * 8 + 4];
        float gv[8] = {g0.x, g0.y, g0.z, g0.w, g1.x, g1.y, g1.z, g1.w};
        float bv[8] = {b0.x, b0.y, b0.z, b0.w, b1v.x, b1v.y, b1v.z, b1v.w};
        __syncthreads();
        unsigned int* hw = (unsigned int*)&bufF[lstripe][0];
        #pragma unroll
        for (int jj = 0; jj < 4; ++jj) {
            float h0 = fmaxf((vv[2 * jj] - mu) * rs * gv[2 * jj] + bv[2 * jj], 0.f);
            float h1 = fmaxf((vv[2 * jj + 1] - mu) * rs * gv[2 * jj + 1] + bv[2 * jj + 1], 0.f);
            hw[lr * 33 + sq * 4 + jj] = f2bf(h0) | (f2bf(h1) << 16);
        }
    }
    __syncthreads();

    // ---- GEMM2: h(16x64) @ Wc(64x320); wave does 10 of 20 col-blocks ----
    bh8 a2[2];
    #pragma unroll
    for (int ks = 0; ks < 2; ++ks)
        a2[ks] = *(const bh8*)&hU[l15 * 33 + ks * 16 + g4 * 4];
    int ndg = row0 + g4 * 4;
    #pragma unroll 2
    for (int nn = 0; nn < 10; ++nn) {
        int nb = half * 10 + nn;
        fx4 c = (fx4){0.f, 0.f, 0.f, 0.f};
        #pragma unroll
        for (int ks = 0; ks < 2; ++ks) {
            bh8 bf = *(const bh8*)(WcT + ((size_t)(nb * 16 + l15) * 64 + ks * 32 + g4 * 8));
            c = __builtin_amdgcn_mfma_f32_16x16x32_bf16(a2[ks], bf, c, 0, 0, 0);
        }
        int col = nb * 16 + l15;
        #pragma unroll
        for (int r = 0; r < 4; ++r) {
            int nd = ndg + r;
            if (nd >= N_NODES) continue;
            float v = c[r];
            if (col < 128) {
                AbfO[(size_t)nd * 128 + col] = f2bfu(v + b1[col]);
            } else if (col < 256) {
                unsigned int p = __builtin_amdgcn_cvt_pk_fp8_f32(v, v, 0, false);
                B8O[(size_t)nd * 128 + (col - 128)] = (unsigned char)(p & 0xFF);
            } else {
                Rbf[(size_t)nd * 64 + (col - 256)] = f2bfu(v);
            }
        }
    }
}

extern "C" void kernel_launch(void* const* d_in, const int* in_sizes, int n_in,
                              void* d_out, int out_size, void* d_ws, size_t ws_size,
                              hipStream_t stream) {
    const float* x       = (const float*)d_in[0];
    const int*   ei      = (const int*)d_in[1];
    const float* encW    = (const float*)d_in[2];
    const float* encb    = (const float*)d_in[3];
    const float* encg    = (const float*)d_in[4];
    const float* encbeta = (const float*)d_in[5];
    const float* lng     = (const float*)d_in[6];
    const float* lnb     = (const float*)d_in[7];
    const float* W1      = (const float*)d_in[8];
    const float* b1      = (const float*)d_in[9];
    const float* W2      = (const float*)d_in[10];
    const float* b2      = (const float*)d_in[11];
    const float* Wr      = (const float*)d_in[12];
    float* xout = (float*)d_out;

    char* ws = (char*)d_ws;
    size_t off = 0;
    auto alloc = [&](size_t bytes) -> void* {
        void* p = ws + off;
        off += (bytes + 255) & ~(size_t)255;
        return p;
    };
    unsigned short* WcT  = (unsigned short*)alloc(3 * 320 * 64 * sizeof(unsigned short));
    unsigned short* W2T  = (unsigned short*)alloc(3 * 64 * 128 * sizeof(unsigned short));
    unsigned short* Abf0 = (unsigned short*)alloc((size_t)N_NODES * 128 * sizeof(unsigned short));
    unsigned short* Abf1 = (unsigned short*)alloc((size_t)N_NODES * 128 * sizeof(unsigned short));
    unsigned char*  B80  = (unsigned char*)alloc((size_t)N_NODES * 128);
    unsigned char*  B81  = (unsigned char*)alloc((size_t)N_NODES * 128);
    unsigned short* Rbf  = (unsigned short*)alloc((size_t)N_NODES * 64 * sizeof(unsigned short));
    int*            cnt  = (int*)alloc(N_NODES * sizeof(int));
    int*            rp   = (int*)alloc((N_NODES + 1) * sizeof(int));
    int*            el   = (int*)alloc(N_EDGES * sizeof(int));
    int*            exw  = (int*)alloc(N_NODES * sizeof(int));
    int*            bsum = (int*)alloc(SCAN_NB * sizeof(int));

    hipMemsetAsync(cnt, 0, N_NODES * sizeof(int), stream);
    hist_kernel<<<(N_EDGES + 255) / 256, 256, 0, stream>>>(ei, cnt);
    scan1_kernel<<<SCAN_NB, 1024, 0, stream>>>(cnt, exw, bsum);
    scan3_kernel<<<SCAN_NB, 1024, 0, stream>>>(exw, bsum, rp, cnt);
    fill_kernel<<<(N_EDGES + 255) / 256, 256, 0, stream>>>(ei, rp, cnt, el);
    repack_kernel<<<(WCT_TOT + W2T_TOT + 255) / 256, 256, 0, stream>>>(W1, Wr, W2, WcT, W2T);

    encoder_kernel<<<(N_NODES + 3) / 4, 256, 0, stream>>>(x, encW, encb, encg, encbeta, xout);

    int gblocks = (N_NODES + 31) / 32;
    // layer 0: LN+GEMM only, writes pair0
    fused6_kernel<<<gblocks, 256, 0, stream>>>(
        xout, Abf0, B80, W2T, b2, rp, el, lng, lnb,
        WcT, b1, Abf0, B80, Rbf, 0);
    // layer 1: gather pair0 (layer0 W2), writes pair1
    fused6_kernel<<<gblocks, 256, 0, stream>>>(
        xout, Abf0, B80, W2T, b2, rp, el, lng + 64, lnb + 64,
        WcT + (size_t)1 * 320 * 64, b1 + 128, Abf1, B81, Rbf, 1);
    // layer 2: gather pair1 (layer1 W2), writes pair0
    fused6_kernel<<<gblocks, 256, 0, stream>>>(
        xout, Abf1, B81, W2T + (size_t)1 * 64 * 128, b2 + 64, rp, el, lng + 128, lnb + 128,
        WcT + (size_t)2 * 320 * 64, b1 + 256, Abf0, B80, Rbf, 1);
    // final: gather pair0 (layer2 W2), update only
    fused6_kernel<<<gblocks, 256, 0, stream>>>(
        xout, Abf0, B80, W2T + (size_t)2 * 64 * 128, b2 + 128, rp, el, lng, lnb,
        WcT, b1, Abf1, B81, Rbf, 2);
}

// Round 10
// 229.175 us; speedup vs baseline: 2.0087x; 1.0810x over previous
//
#include <hip/hip_runtime.h>
#include <hip/hip_bf16.h>

#define N_NODES 50000
#define N_EDGES 400000
#define IN_CH 32
#define EPS 1e-5f
#define SCAN_NB ((N_NODES + 1023) / 1024)
#define EL_CAP 384

typedef __attribute__((ext_vector_type(8))) short bh8;
typedef __attribute__((ext_vector_type(4))) float fx4;
typedef __attribute__((ext_vector_type(2))) float fx2;

static __device__ __forceinline__ unsigned int f2bf(float f) {
    __hip_bfloat16 h = __float2bfloat16(f);
    return (unsigned int)*(unsigned short*)&h;
}
static __device__ __forceinline__ unsigned short f2bfu(float f) {
    __hip_bfloat16 h = __float2bfloat16(f);
    return *(unsigned short*)&h;
}
static __device__ __forceinline__ float bflo(unsigned int u) { return __uint_as_float(u << 16); }
static __device__ __forceinline__ float bfhi(unsigned int u) { return __uint_as_float(u & 0xffff0000u); }

// ---------------- CSR build ----------------
__global__ void hist_kernel(const int* __restrict__ ei, int* __restrict__ cnt) {
    int e = blockIdx.x * 256 + threadIdx.x;
    if (e < N_EDGES) atomicAdd(&cnt[ei[N_EDGES + e]], 1);
}

__global__ __launch_bounds__(1024) void scan1_kernel(const int* __restrict__ cnt,
                                                     int* __restrict__ exw,
                                                     int* __restrict__ bsum) {
    int b = blockIdx.x, t = threadIdx.x;
    int i = b * 1024 + t;
    int v = (i < N_NODES) ? cnt[i] : 0;
    int lane = t & 63, w = t >> 6;
    int s = v;
    #pragma unroll
    for (int off = 1; off < 64; off <<= 1) {
        int u = __shfl_up(s, off, 64);
        if (lane >= off) s += u;
    }
    __shared__ int ws[16];
    if (lane == 63) ws[w] = s;
    __syncthreads();
    if (t < 16) {
        int sv = ws[t];
        #pragma unroll
        for (int off = 1; off < 16; off <<= 1) {
            int u = __shfl_up(sv, off, 64);
            if (lane >= off) sv += u;
        }
        ws[t] = sv;
    }
    __syncthreads();
    int prefix = (w > 0) ? ws[w - 1] : 0;
    int incl = s + prefix;
    if (i < N_NODES) exw[i] = incl - v;
    if (t == 1023) bsum[b] = incl;
}

__global__ __launch_bounds__(1024) void scan3_kernel(const int* __restrict__ exw,
                                                     const int* __restrict__ bsum,
                                                     int* __restrict__ rp,
                                                     int* __restrict__ cnt) {
    __shared__ int pfx;
    __shared__ int total;
    int b = blockIdx.x, t = threadIdx.x;
    if (t < 64) {
        int v = (t < SCAN_NB) ? bsum[t] : 0;
        #pragma unroll
        for (int off = 1; off < 64; off <<= 1) {
            int u = __shfl_up(v, off, 64);
            if (t >= off) v += u;
        }
        if (b == 0 && t == 0) pfx = 0;
        if (b > 0 && t == b - 1) pfx = v;
        if (t == SCAN_NB - 1) total = v;
    }
    __syncthreads();
    int i = b * 1024 + t;
    if (i < N_NODES) {
        rp[i] = exw[i] + pfx;
        cnt[i] = 0;
    }
    if (b == 0 && t == 0) rp[N_NODES] = total;
}

__global__ void fill_kernel(const int* __restrict__ ei, const int* __restrict__ rp,
                            int* __restrict__ cur, int* __restrict__ el) {
    int e = blockIdx.x * 256 + threadIdx.x;
    if (e < N_EDGES) {
        int d = ei[N_EDGES + e];
        int p = atomicAdd(&cur[d], 1);
        el[rp[d] + p] = ei[e];
    }
}

// ---------------- merged weight prepacks ----------------
#define WCT_TOT (3 * 320 * 64)
#define W2T_TOT (3 * 64 * 128)
__global__ void repack_kernel(const float* __restrict__ W1, const float* __restrict__ Wr,
                              const float* __restrict__ W2,
                              unsigned short* __restrict__ WcT,
                              unsigned short* __restrict__ W2T) {
    int t = blockIdx.x * 256 + threadIdx.x;
    if (t < WCT_TOT) {
        int l = t / (320 * 64);
        int rem = t % (320 * 64);
        int j = rem / 64, c = rem % 64;
        float v;
        if (j < 128)      v = W1[(l * 128 + c) * 128 + j];
        else if (j < 256) v = W1[(l * 128 + 64 + c) * 128 + (j - 128)];
        else              v = Wr[(l * 64 + c) * 64 + (j - 256)];
        WcT[t] = f2bfu(v);
    } else if (t < WCT_TOT + W2T_TOT) {
        int t2 = t - WCT_TOT;
        int l = t2 / 8192, rem = t2 % 8192;
        int n = rem / 128, k = rem % 128;
        W2T[t2] = f2bfu(W2[l * 8192 + k * 64 + n]);
    }
}

// ---------------- encoder ----------------
__global__ __launch_bounds__(256) void encoder_kernel(
    const float* __restrict__ x, const float* __restrict__ W,
    const float* __restrict__ b, const float* __restrict__ g,
    const float* __restrict__ beta, float* __restrict__ out) {
    __shared__ float wlds[IN_CH * 64];
    for (int t = threadIdx.x; t < IN_CH * 64; t += 256) wlds[t] = W[t];
    __syncthreads();
    int lane = threadIdx.x & 63;
    int node = blockIdx.x * 4 + (threadIdx.x >> 6);
    if (node >= N_NODES) return;
    float xv = (lane < IN_CH) ? x[node * IN_CH + lane] : 0.f;
    float acc = b[lane];
    #pragma unroll
    for (int c = 0; c < IN_CH; ++c) {
        float xc = __shfl(xv, c, 64);
        acc += xc * wlds[c * 64 + lane];
    }
    float s = acc;
    for (int off = 32; off; off >>= 1) s += __shfl_xor(s, off, 64);
    float mu = s * (1.f / 64.f);
    float d = acc - mu;
    float q = d * d;
    for (int off = 32; off; off >>= 1) q += __shfl_xor(q, off, 64);
    float r = rsqrtf(q * (1.f / 64.f) + EPS);
    out[node * 64 + lane] = d * r * g[lane] + beta[lane];
}

// ---------------- fused7: 16-node tiles, 256 thr (4 waves), 16 threads/node gather
// mode 0: LN+GEMM only. mode 1: full. mode 2: gather+update only.
__global__ __launch_bounds__(256, 8) void fused7_kernel(
    float* __restrict__ x,
    const unsigned int* __restrict__ AbfI, const unsigned char* __restrict__ B8I,
    const unsigned short* __restrict__ W2T, const float* __restrict__ b2,
    const int* __restrict__ rp, const int* __restrict__ el,
    const float* __restrict__ g, const float* __restrict__ bvec,
    const unsigned short* __restrict__ WcT, const float* __restrict__ b1,
    unsigned short* __restrict__ AbfO, unsigned char* __restrict__ B8O,
    unsigned short* __restrict__ Rbf, int mode) {
    __shared__ float bufF[1088];          // xf rows stride 68 ; later h rows stride 33 (uints)
    __shared__ unsigned int slds[16][68]; // gathered S tile, bf16 pairs
    __shared__ int el_lds[EL_CAP];
    __shared__ int rp_lds[17];
    int tid = threadIdx.x;
    int lane = tid & 63, wid = tid >> 6;
    int l15 = lane & 15, g4 = lane >> 4;
    int base = blockIdx.x * 16;
    unsigned int* hU = (unsigned int*)bufF;
    int n = tid >> 4, sq = tid & 15;  // gather/LN mapping: 16 threads per row

    int col = wid * 16 + l15;         // epilogue column
    int nd_l = base + g4 * 4;         // epilogue row group

    if (mode != 0) {
        if (tid < 17) rp_lds[tid] = rp[min(base + tid, N_NODES)];
        __syncthreads();
        int e0 = rp_lds[0];
        int nE = rp_lds[16] - e0;
        bool inl = (nE <= EL_CAP);
        if (inl) for (int t = tid; t < nE; t += 256) el_lds[t] = el[e0 + t];

        // own-node A row segment: 8 cols per thread
        int nd_g = base + n;
        float av[8], acc[8];
        #pragma unroll
        for (int i = 0; i < 8; ++i) { av[i] = 0.f; acc[i] = 0.f; }
        {
            uint4 a0 = *(const uint4*)(AbfI + (size_t)min(nd_g, N_NODES - 1) * 64 + sq * 4);
            unsigned int aw[4] = {a0.x, a0.y, a0.z, a0.w};
            #pragma unroll
            for (int q = 0; q < 4; ++q) { av[2 * q] = bflo(aw[q]); av[2 * q + 1] = bfhi(aw[q]); }
        }
        __syncthreads();  // el_lds ready

        // ---- 8-deep batched gather: 8 B per thread per edge ----
        int es = rp_lds[n] - e0, ee = rp_lds[n + 1] - e0;
        int e2 = es;
        int cn = ee - e2; if (cn > 8) cn = 8;
        uint2 bufv[8];
        #pragma unroll
        for (int j = 0; j < 8; ++j)
            if (j < cn) {
                int src = inl ? el_lds[e2 + j] : el[e0 + e2 + j];
                bufv[j] = *(const uint2*)(B8I + (size_t)src * 128 + sq * 8);
            }
        while (cn > 0) {
            #pragma unroll
            for (int j = 0; j < 8; ++j)
                if (j < cn) {
                    fx2 f0 = __builtin_amdgcn_cvt_pk_f32_fp8((int)bufv[j].x, false);
                    fx2 f1 = __builtin_amdgcn_cvt_pk_f32_fp8((int)bufv[j].x, true);
                    fx2 f2 = __builtin_amdgcn_cvt_pk_f32_fp8((int)bufv[j].y, false);
                    fx2 f3 = __builtin_amdgcn_cvt_pk_f32_fp8((int)bufv[j].y, true);
                    acc[0] += fmaxf(av[0] + f0.x, 0.f);
                    acc[1] += fmaxf(av[1] + f0.y, 0.f);
                    acc[2] += fmaxf(av[2] + f1.x, 0.f);
                    acc[3] += fmaxf(av[3] + f1.y, 0.f);
                    acc[4] += fmaxf(av[4] + f2.x, 0.f);
                    acc[5] += fmaxf(av[5] + f2.y, 0.f);
                    acc[6] += fmaxf(av[6] + f3.x, 0.f);
                    acc[7] += fmaxf(av[7] + f3.y, 0.f);
                }
            e2 += cn;
            cn = ee - e2; if (cn > 8) cn = 8;
            #pragma unroll
            for (int j = 0; j < 8; ++j)
                if (j < cn) {
                    int src = inl ? el_lds[e2 + j] : el[e0 + e2 + j];
                    bufv[j] = *(const uint2*)(B8I + (size_t)src * 128 + sq * 8);
                }
        }
        #pragma unroll
        for (int jj = 0; jj < 4; ++jj)
            slds[n][sq * 4 + jj] = f2bf(acc[2 * jj]) | (f2bf(acc[2 * jj + 1]) << 16);

        // epilogue operand prefetch (overlaps barrier + MFMA)
        float xpre[4], rpre[4];
        #pragma unroll
        for (int r = 0; r < 4; ++r) {
            int nd = min(nd_l + r, N_NODES - 1);
            xpre[r] = x[(size_t)nd * 64 + col];
            rpre[r] = bflo((unsigned int)Rbf[(size_t)nd * 64 + col]);
        }
        __syncthreads();

        // ---- S(16x128) @ W2T -> update x ; wave wid owns cols wid*16..+15 ----
        bh8 sa[4];
        #pragma unroll
        for (int ks = 0; ks < 4; ++ks)
            sa[ks] = *(const bh8*)&slds[l15][ks * 16 + g4 * 4];
        fx4 accm = (fx4){0.f, 0.f, 0.f, 0.f};
        #pragma unroll
        for (int ks = 0; ks < 4; ++ks) {
            bh8 bf = *(const bh8*)(W2T + ((size_t)(wid * 16 + l15) * 128 + ks * 32 + g4 * 8));
            accm = __builtin_amdgcn_mfma_f32_16x16x32_bf16(sa[ks], bf, accm, 0, 0, 0);
        }
        float b2c = b2[col];
        #pragma unroll
        for (int r = 0; r < 4; ++r) {
            int lcl = g4 * 4 + r;
            int cv = rp_lds[lcl + 1] - rp_lds[lcl];
            float inv = cv > 0 ? 1.f / (float)cv : 0.f;
            float msk = cv > 0 ? 1.f : 0.f;
            int nd = nd_l + r;
            float xn = xpre[r] + accm[r] * inv + b2c * msk + rpre[r];
            if (nd < N_NODES) x[(size_t)nd * 64 + col] = xn;
            if (mode == 1) bufF[lcl * 68 + col] = xn;
        }
        if (mode == 2) return;
        __syncthreads();
    }

    // ---- LN + ReLU: 16 threads per row, 4 cols each; write h bf16x2 stride 33 ----
    {
        float vv[4];
        if (mode == 0) {
            int nd = base + n;
            float4 v0 = make_float4(0.f, 0.f, 0.f, 0.f);
            if (nd < N_NODES) v0 = ((const float4*)(x + (size_t)nd * 64))[sq];
            vv[0] = v0.x; vv[1] = v0.y; vv[2] = v0.z; vv[3] = v0.w;
        } else {
            #pragma unroll
            for (int i = 0; i < 4; ++i) vv[i] = bufF[n * 68 + sq * 4 + i];
        }
        float s = vv[0] + vv[1] + vv[2] + vv[3];
        s += __shfl_xor(s, 1, 16);
        s += __shfl_xor(s, 2, 16);
        s += __shfl_xor(s, 4, 16);
        s += __shfl_xor(s, 8, 16);
        float mu = s * (1.f / 64.f);
        float q = 0.f;
        #pragma unroll
        for (int i = 0; i < 4; ++i) { float d = vv[i] - mu; q += d * d; }
        q += __shfl_xor(q, 1, 16);
        q += __shfl_xor(q, 2, 16);
        q += __shfl_xor(q, 4, 16);
        q += __shfl_xor(q, 8, 16);
        float rs = rsqrtf(q * (1.f / 64.f) + EPS);
        float4 gg = *(const float4*)&g[sq * 4];
        float4 bb = *(const float4*)&bvec[sq * 4];
        float gv[4] = {gg.x, gg.y, gg.z, gg.w};
        float bv[4] = {bb.x, bb.y, bb.z, bb.w};
        __syncthreads();  // all bufF reads done before h overwrites
        #pragma unroll
        for (int jj = 0; jj < 2; ++jj) {
            float h0 = fmaxf((vv[2 * jj] - mu) * rs * gv[2 * jj] + bv[2 * jj], 0.f);
            float h1 = fmaxf((vv[2 * jj + 1] - mu) * rs * gv[2 * jj + 1] + bv[2 * jj + 1], 0.f);
            hU[n * 33 + sq * 2 + jj] = f2bf(h0) | (f2bf(h1) << 16);
        }
    }
    __syncthreads();

    // ---- GEMM2: h(16x64) @ Wc(64x320); wave does 5 of 20 col-blocks ----
    bh8 a2[2];
    #pragma unroll
    for (int ks = 0; ks < 2; ++ks)
        a2[ks] = *(const bh8*)&hU[l15 * 33 + ks * 16 + g4 * 4];
    int ndg = base + g4 * 4;
    #pragma unroll
    for (int nn = 0; nn < 5; ++nn) {
        int nb = wid * 5 + nn;
        fx4 c = (fx4){0.f, 0.f, 0.f, 0.f};
        #pragma unroll
        for (int ks = 0; ks < 2; ++ks) {
            bh8 bf = *(const bh8*)(WcT + ((size_t)(nb * 16 + l15) * 64 + ks * 32 + g4 * 8));
            c = __builtin_amdgcn_mfma_f32_16x16x32_bf16(a2[ks], bf, c, 0, 0, 0);
        }
        int colw = nb * 16 + l15;
        #pragma unroll
        for (int r = 0; r < 4; ++r) {
            int nd = ndg + r;
            if (nd >= N_NODES) continue;
            float v = c[r];
            if (colw < 128) {
                ((unsigned short*)AbfO)[(size_t)nd * 128 + colw] = f2bfu(v + b1[colw]);
            } else if (colw < 256) {
                unsigned int p = __builtin_amdgcn_cvt_pk_fp8_f32(v, v, 0, false);
                B8O[(size_t)nd * 128 + (colw - 128)] = (unsigned char)(p & 0xFF);
            } else {
                Rbf[(size_t)nd * 64 + (colw - 256)] = f2bfu(v);
            }
        }
    }
}

extern "C" void kernel_launch(void* const* d_in, const int* in_sizes, int n_in,
                              void* d_out, int out_size, void* d_ws, size_t ws_size,
                              hipStream_t stream) {
    const float* x       = (const float*)d_in[0];
    const int*   ei      = (const int*)d_in[1];
    const float* encW    = (const float*)d_in[2];
    const float* encb    = (const float*)d_in[3];
    const float* encg    = (const float*)d_in[4];
    const float* encbeta = (const float*)d_in[5];
    const float* lng     = (const float*)d_in[6];
    const float* lnb     = (const float*)d_in[7];
    const float* W1      = (const float*)d_in[8];
    const float* b1      = (const float*)d_in[9];
    const float* W2      = (const float*)d_in[10];
    const float* b2      = (const float*)d_in[11];
    const float* Wr      = (const float*)d_in[12];
    float* xout = (float*)d_out;

    char* ws = (char*)d_ws;
    size_t off = 0;
    auto alloc = [&](size_t bytes) -> void* {
        void* p = ws + off;
        off += (bytes + 255) & ~(size_t)255;
        return p;
    };
    unsigned short* WcT  = (unsigned short*)alloc(3 * 320 * 64 * sizeof(unsigned short));
    unsigned short* W2T  = (unsigned short*)alloc(3 * 64 * 128 * sizeof(unsigned short));
    unsigned int*   Abf0 = (unsigned int*)alloc((size_t)N_NODES * 128 * sizeof(unsigned short));
    unsigned int*   Abf1 = (unsigned int*)alloc((size_t)N_NODES * 128 * sizeof(unsigned short));
    unsigned char*  B80  = (unsigned char*)alloc((size_t)N_NODES * 128);
    unsigned char*  B81  = (unsigned char*)alloc((size_t)N_NODES * 128);
    unsigned short* Rbf  = (unsigned short*)alloc((size_t)N_NODES * 64 * sizeof(unsigned short));
    int*            cnt  = (int*)alloc(N_NODES * sizeof(int));
    int*            rp   = (int*)alloc((N_NODES + 1) * sizeof(int));
    int*            el   = (int*)alloc(N_EDGES * sizeof(int));
    int*            exw  = (int*)alloc(N_NODES * sizeof(int));
    int*            bsum = (int*)alloc(SCAN_NB * sizeof(int));

    hipMemsetAsync(cnt, 0, N_NODES * sizeof(int), stream);
    hist_kernel<<<(N_EDGES + 255) / 256, 256, 0, stream>>>(ei, cnt);
    scan1_kernel<<<SCAN_NB, 1024, 0, stream>>>(cnt, exw, bsum);
    scan3_kernel<<<SCAN_NB, 1024, 0, stream>>>(exw, bsum, rp, cnt);
    fill_kernel<<<(N_EDGES + 255) / 256, 256, 0, stream>>>(ei, rp, cnt, el);
    repack_kernel<<<(WCT_TOT + W2T_TOT + 255) / 256, 256, 0, stream>>>(W1, Wr, W2, WcT, W2T);

    encoder_kernel<<<(N_NODES + 3) / 4, 256, 0, stream>>>(x, encW, encb, encg, encbeta, xout);

    int gblocks = (N_NODES + 15) / 16;
    // layer 0: LN+GEMM only, writes pair0
    fused7_kernel<<<gblocks, 256, 0, stream>>>(
        xout, Abf0, B80, W2T, b2, rp, el, lng, lnb,
        WcT, b1, (unsigned short*)Abf0, B80, Rbf, 0);
    // layer 1: gather pair0 (layer0 W2), writes pair1
    fused7_kernel<<<gblocks, 256, 0, stream>>>(
        xout, Abf0, B80, W2T, b2, rp, el, lng + 64, lnb + 64,
        WcT + (size_t)1 * 320 * 64, b1 + 128, (unsigned short*)Abf1, B81, Rbf, 1);
    // layer 2: gather pair1 (layer1 W2), writes pair0
    fused7_kernel<<<gblocks, 256, 0, stream>>>(
        xout, Abf1, B81, W2T + (size_t)1 * 64 * 128, b2 + 64, rp, el, lng + 128, lnb + 128,
        WcT + (size_t)2 * 320 * 64, b1 + 256, (unsigned short*)Abf0, B80, Rbf, 1);
    // final: gather pair0 (layer2 W2), update only
    fused7_kernel<<<gblocks, 256, 0, stream>>>(
        xout, Abf0, B80, W2T + (size_t)2 * 64 * 128, b2 + 128, rp, el, lng, lnb,
        WcT, b1, (unsigned short*)Abf1, B81, Rbf, 2);
}